// Round 10
// baseline (220.695 us; speedup 1.0000x reference)
//
#include <hip/hip_runtime.h>
#include <hip/hip_bf16.h>

#define N_NODES 50000
#define N_EDGES 800000
#define ET      (N_EDGES + N_NODES)   // edges + self loops = 850000
#define IN_DIM  128
#define HID     64
#define HEADS   4
#define C1      (HEADS * HID)         // 256
#define NEG_SLOPE 0.2f

#define NBH     256                    // histogram/scatter blocks
#define NBUCKET 196                    // ceil(50000/256) coarse buckets (dst>>8)
#define SCAN_N  (NBUCKET * NBH)        // 50176

typedef unsigned short ushort_t;
typedef __attribute__((ext_vector_type(8))) short bf16x8;
typedef __attribute__((ext_vector_type(4))) float f32x4;

__device__ __forceinline__ float asf(unsigned int u) {
    union { unsigned int i; float f; } c; c.i = u; return c.f;
}
__device__ __forceinline__ float bf2f(ushort_t u) {
    return asf(((unsigned int)u) << 16);
}
__device__ __forceinline__ ushort_t f2bf(float f) {
    union { float f; unsigned int i; } c; c.f = f;
    unsigned int r = c.i + 0x7fffu + ((c.i >> 16) & 1u);   // RNE
    return (ushort_t)(r >> 16);
}
__device__ __forceinline__ float lrelu(float x) { return x > 0.f ? x : NEG_SLOPE * x; }

__device__ __forceinline__ float wave_sum(float v) {
    #pragma unroll
    for (int off = 32; off > 0; off >>= 1) v += __shfl_xor(v, off, 64);
    return v;
}
__device__ __forceinline__ int wave_sum_i(int v) {
    #pragma unroll
    for (int off = 32; off > 0; off >>= 1) v += __shfl_xor(v, off, 64);
    return v;
}

__device__ __forceinline__ int load_idx(const int* ei, int elem, int is64) {
    return is64 ? ei[2 * elem] : ei[elem];   // little-endian low word
}

// int64 edge_index detector (int64 data has all-zero high words).
__device__ __forceinline__ int detect64(const int* __restrict__ ei) {
    int lane = threadIdx.x & 63;
    unsigned long long nz = __ballot(lane < 32 && ei[2 * lane + 1] != 0);
    return nz == 0ull;
}

// ---------------- CSR build phase 1: coarse histogram (+ W1 swizzle folded in) ----------------
__global__ __launch_bounds__(256) void k_hist(const int* __restrict__ ei,
                                              int* __restrict__ HT,
                                              const float* __restrict__ W1,
                                              ushort_t* __restrict__ w1s) {
    __shared__ int lcnt[NBUCKET];
    int f = detect64(ei);
    if (threadIdx.x < NBUCKET) lcnt[threadIdx.x] = 0;
    if (threadIdx.x < 128) {           // fold: W1 -> bf16 B-fragment swizzle
        int o = blockIdx.x * 128 + threadIdx.x;
        int j = o & 7, l = (o >> 3) & 63, c = (o >> 9) & 3, t = o >> 11;
        int k = c * 32 + ((l >> 4) << 3) + j;
        int n = (t << 4) + (l & 15);
        w1s[o] = f2bf(W1[k * C1 + n]);
    }
    __syncthreads();
    for (int e = blockIdx.x * 256 + threadIdx.x; e < ET; e += NBH * 256) {
        int d = (e < N_EDGES) ? load_idx(ei, N_EDGES + e, f) : e - N_EDGES;
        atomicAdd(&lcnt[d >> 8], 1);        // LDS atomic
    }
    __syncthreads();
    if (threadIdx.x < NBUCKET)
        HT[threadIdx.x * NBH + blockIdx.x] = lcnt[threadIdx.x];
}

// ---------------- scan of HT (50176 ints, bucket-major) ----------------
__global__ __launch_bounds__(256) void k_blksum(const int* __restrict__ v,
                                                int* __restrict__ bsum) {
    int i = blockIdx.x * 256 + threadIdx.x;
    int s = wave_sum_i(v[i]);
    __shared__ int ws[4];
    int lane = threadIdx.x & 63, wid = threadIdx.x >> 6;
    if (lane == 0) ws[wid] = s;
    __syncthreads();
    if (threadIdx.x == 0) bsum[blockIdx.x] = ws[0] + ws[1] + ws[2] + ws[3];
}

__global__ __launch_bounds__(256) void k_bscan(const int* __restrict__ bsum,
                                               int* __restrict__ boff) {
    int tid = threadIdx.x, lane = tid & 63, wid = tid >> 6;
    int v = (tid < NBUCKET) ? bsum[tid] : 0;
    int x = v;
    #pragma unroll
    for (int off = 1; off < 64; off <<= 1) {
        int t = __shfl_up(x, off, 64);
        if (lane >= off) x += t;
    }
    __shared__ int ws[4];
    if (lane == 63) ws[wid] = x;
    __syncthreads();
    int add = 0;
    for (int w = 0; w < 4; ++w) if (w < wid) add += ws[w];
    x += add;
    if (tid < NBUCKET) boff[tid] = x - v;
}

__global__ __launch_bounds__(256) void k_apply(const int* __restrict__ v,
                                               const int* __restrict__ boff,
                                               int* __restrict__ out) {
    int i = blockIdx.x * 256 + threadIdx.x;
    int lane = threadIdx.x & 63, wid = threadIdx.x >> 6;
    int val = v[i];
    int x = val;
    #pragma unroll
    for (int off = 1; off < 64; off <<= 1) {
        int t = __shfl_up(x, off, 64);
        if (lane >= off) x += t;
    }
    __shared__ int ws[4];
    if (lane == 63) ws[wid] = x;
    __syncthreads();
    int add = boff[blockIdx.x];
    for (int w = 0; w < 4; ++w) if (w < wid) add += ws[w];
    out[i] = add + x - val;
}

// ---------------- CSR phase 3: bucket scatter (LDS-atomic ranks) ----------------
__global__ __launch_bounds__(256) void k_bucket_scatter(const int* __restrict__ ei,
                                                        const int* __restrict__ HToff,
                                                        uint2* __restrict__ bucketed) {
    __shared__ int lbase[NBUCKET];
    int f = detect64(ei);
    if (threadIdx.x < NBUCKET)
        lbase[threadIdx.x] = HToff[threadIdx.x * NBH + blockIdx.x];
    __syncthreads();
    for (int e = blockIdx.x * 256 + threadIdx.x; e < ET; e += NBH * 256) {
        int s, d;
        if (e < N_EDGES) { s = load_idx(ei, e, f); d = load_idx(ei, N_EDGES + e, f); }
        else             { s = d = e - N_EDGES; }
        int pos = atomicAdd(&lbase[d >> 8], 1);
        bucketed[pos] = make_uint2((unsigned)s, (unsigned)d);
    }
}

// ---------------- CSR phase 4: per-bucket fine CSR ----------------
__global__ __launch_bounds__(256) void k_fine(const uint2* __restrict__ bucketed,
                                              const int* __restrict__ HToff,
                                              int* __restrict__ row_start,
                                              int* __restrict__ edge_src) {
    __shared__ int fcnt[256];
    __shared__ int fcur[256];
    __shared__ int ws[4];
    int b = blockIdx.x, tid = threadIdx.x;
    int lane = tid & 63, wid = tid >> 6;
    int estart = HToff[b * NBH];
    int eend   = (b + 1 < NBUCKET) ? HToff[(b + 1) * NBH] : ET;
    fcnt[tid] = 0;
    __syncthreads();
    for (int i = estart + tid; i < eend; i += 256)
        atomicAdd(&fcnt[bucketed[i].y & 255], 1);
    __syncthreads();
    int v = fcnt[tid];
    int x = v;
    #pragma unroll
    for (int off = 1; off < 64; off <<= 1) {
        int t = __shfl_up(x, off, 64);
        if (lane >= off) x += t;
    }
    if (lane == 63) ws[wid] = x;
    __syncthreads();
    int add = 0;
    for (int w = 0; w < 4; ++w) if (w < wid) add += ws[w];
    int excl = add + x - v;
    int node = b * 256 + tid;
    if (node <= N_NODES) row_start[node] = estart + excl;
    fcur[tid] = estart + excl;
    __syncthreads();
    for (int i = estart + tid; i < eend; i += 256) {
        uint2 u = bucketed[i];
        int pos = atomicAdd(&fcur[u.y & 255], 1);
        edge_src[pos] = (int)u.x;
    }
}

// ---------------- Layer 1 GEMM (MFMA) + fused attention-logit epilogue ----------------
__global__ __launch_bounds__(256) void k_gemm1(const float* __restrict__ x,
                                               const ushort_t* __restrict__ w1s,
                                               const float* __restrict__ a_src1,
                                               const float* __restrict__ a_dst1,
                                               ushort_t* __restrict__ h1,
                                               float* __restrict__ as1,
                                               float* __restrict__ ad1) {
    int lane = threadIdx.x & 63;
    int wave = (blockIdx.x * 256 + threadIdx.x) >> 6;
    int row0 = wave * 16;
    if (row0 >= N_NODES) return;
    int quad = lane >> 4, mrow = lane & 15;

    f32x4 acc[16];
    #pragma unroll
    for (int t = 0; t < 16; ++t) acc[t] = (f32x4){0.f, 0.f, 0.f, 0.f};

    const float* xrow = x + (size_t)(row0 + mrow) * IN_DIM + quad * 8;
    #pragma unroll
    for (int c = 0; c < 4; ++c) {
        float4 xa = *(const float4*)(xrow + c * 32);
        float4 xb = *(const float4*)(xrow + c * 32 + 4);
        bf16x8 a;
        a[0] = (short)f2bf(xa.x); a[1] = (short)f2bf(xa.y);
        a[2] = (short)f2bf(xa.z); a[3] = (short)f2bf(xa.w);
        a[4] = (short)f2bf(xb.x); a[5] = (short)f2bf(xb.y);
        a[6] = (short)f2bf(xb.z); a[7] = (short)f2bf(xb.w);
        #pragma unroll
        for (int t = 0; t < 16; ++t) {
            bf16x8 b = *(const bf16x8*)(w1s + (((t * 4 + c) * 64 + lane) << 3));
            acc[t] = __builtin_amdgcn_mfma_f32_16x16x32_bf16(a, b, acc[t], 0, 0, 0);
        }
    }

    #pragma unroll
    for (int t = 0; t < 16; ++t) {
        int col = t * 16 + mrow;
        #pragma unroll
        for (int r = 0; r < 4; ++r) {
            h1[(size_t)(row0 + quad * 4 + r) * C1 + col] = f2bf(acc[t][r]);
        }
    }

    float asv[16], adv[16];
    #pragma unroll
    for (int t = 0; t < 16; ++t) {
        asv[t] = a_src1[t * 16 + mrow];
        adv[t] = a_dst1[t * 16 + mrow];
    }
    #pragma unroll
    for (int r = 0; r < 4; ++r) {
        float ps[4] = {0.f, 0.f, 0.f, 0.f};
        float pd[4] = {0.f, 0.f, 0.f, 0.f};
        #pragma unroll
        for (int t = 0; t < 16; ++t) {
            ps[t >> 2] += acc[t][r] * asv[t];
            pd[t >> 2] += acc[t][r] * adv[t];
        }
        #pragma unroll
        for (int h = 0; h < 4; ++h) {
            #pragma unroll
            for (int off = 1; off < 16; off <<= 1) {
                ps[h] += __shfl_xor(ps[h], off, 64);
                pd[h] += __shfl_xor(pd[h], off, 64);
            }
        }
        if (mrow == 0) {
            int rr = row0 + quad * 4 + r;
            #pragma unroll
            for (int h = 0; h < 4; ++h) {
                as1[rr * 4 + h] = ps[h];
                ad1[rr * 4 + h] = pd[h];
            }
        }
    }
}

// ---------------- Layer 1 softmax-agg, column-split by XCD parity ----------------
// half = blockIdx.x & 1 (round-robin XCD dispatch => even XCDs touch only the
// first 256 B of each h1 row, odd XCDs the second 256 B => each L2 fetches
// half of h1: total fill ~102 MB instead of 205 MB). Each half computes its
// 2 heads' weights/denominators and a partial layer-2 dot pp[2*node+half].
__global__ __launch_bounds__(256) void k_agg1(const ushort_t* __restrict__ h1,
                                              const float* __restrict__ as1,
                                              const float* __restrict__ ad1,
                                              const int* __restrict__ row_start,
                                              const int* __restrict__ edge_src,
                                              const float* __restrict__ b1,
                                              const float* __restrict__ W2,
                                              float* __restrict__ pp) {
    __shared__ float wbuf[4][64][2];   // [wave][chunk-pos][head-within-half]
    int lane = threadIdx.x & 63;
    int wid  = threadIdx.x >> 6;
    int half = blockIdx.x & 1;
    int node = (blockIdx.x >> 1) * 4 + wid;
    int rs = row_start[node], re = row_start[node + 1];
    float2 ad = *(const float2*)&ad1[node * 4 + 2 * half];
    const int hsel = lane >> 5;            // which of this half's 2 heads
    const int col0 = half * 128 + lane * 2;

    float acc0 = 0.f, acc1 = 0.f;
    float den0 = 0.f, den1 = 0.f;

    for (int base = rs; base < re; base += 64) {
        int i = base + lane;
        int s_l = 0;
        float2 w = make_float2(0.f, 0.f);
        if (i < re) {
            s_l = edge_src[i];
            float2 av = *(const float2*)&as1[s_l * 4 + 2 * half];
            w.x = __expf(lrelu(av.x + ad.x));
            w.y = __expf(lrelu(av.y + ad.y));
        }
        den0 += w.x; den1 += w.y;
        *(float2*)&wbuf[wid][lane][0] = w;
        int m = re - base; if (m > 64) m = 64;
        int j = 0;
        for (; j + 8 <= m; j += 8) {       // 8 dword loads in flight
            int ss[8]; unsigned pq[8]; float gg[8];
            #pragma unroll
            for (int q = 0; q < 8; ++q) ss[q] = __builtin_amdgcn_readlane(s_l, j + q);
            #pragma unroll
            for (int q = 0; q < 8; ++q) {
                pq[q] = *(const unsigned*)(h1 + (size_t)ss[q] * C1 + col0);
                gg[q] = wbuf[wid][j + q][hsel];
            }
            #pragma unroll
            for (int q = 0; q < 8; ++q) {
                acc0 += gg[q] * asf(pq[q] << 16);
                acc1 += gg[q] * asf(pq[q] & 0xffff0000u);
            }
        }
        for (; j < m; ++j) {
            int s0 = __builtin_amdgcn_readlane(s_l, j);
            unsigned p0 = *(const unsigned*)(h1 + (size_t)s0 * C1 + col0);
            float g0 = wbuf[wid][j][hsel];
            acc0 += g0 * asf(p0 << 16);
            acc1 += g0 * asf(p0 & 0xffff0000u);
        }
    }

    float d0 = wave_sum(den0), d1 = wave_sum(den1);
    float dh = hsel == 0 ? d0 : d1;
    float inv = 1.f / (dh + 1e-16f);
    float2 bv = *(const float2*)&b1[col0];
    float o0 = fmaxf(acc0 * inv + bv.x, 0.f);
    float o1 = fmaxf(acc1 * inv + bv.y, 0.f);
    float2 wv = *(const float2*)&W2[col0];
    float part = wave_sum(o0 * wv.x + o1 * wv.y);   // partial 128-col dot
    if (lane == 0) pp[node * 2 + half] = part;
}

// ---------------- Layer 2 softmax-agg + sigmoid (partials combined on the fly) ----------------
__global__ __launch_bounds__(256) void k_agg2(const float* __restrict__ pp,
                                              const int* __restrict__ row_start,
                                              const int* __restrict__ edge_src,
                                              const float* __restrict__ a_src2,
                                              const float* __restrict__ a_dst2,
                                              const float* __restrict__ b2,
                                              float* __restrict__ outp) {
    int lane = threadIdx.x & 63;
    int node = blockIdx.x * 4 + (threadIdx.x >> 6);
    int rs = row_start[node], re = row_start[node + 1];
    float as2v = a_src2[0];
    float2 pd = *(const float2*)&pp[node * 2];
    float adv = (pd.x + pd.y) * a_dst2[0];
    float se = 0.f, wsm = 0.f;
    for (int i = rs + lane; i < re; i += 64) {
        int s = edge_src[i];
        float2 p = *(const float2*)&pp[s * 2];
        float h2s = p.x + p.y;
        float w = __expf(lrelu(h2s * as2v + adv));
        se += w; wsm += w * h2s;
    }
    se = wave_sum(se); wsm = wave_sum(wsm);
    if (lane == 0) {
        float v = wsm / (se + 1e-16f) + b2[0];
        outp[node] = 1.f / (1.f + __expf(-v));
    }
}

extern "C" void kernel_launch(void* const* d_in, const int* in_sizes, int n_in,
                              void* d_out, int out_size, void* d_ws, size_t ws_size,
                              hipStream_t stream) {
    (void)in_sizes; (void)n_in; (void)out_size; (void)ws_size;
    const float* x      = (const float*)d_in[0];
    const int*   ei     = (const int*)  d_in[1];
    const float* W1     = (const float*)d_in[2];
    const float* a_src1 = (const float*)d_in[3];
    const float* a_dst1 = (const float*)d_in[4];
    const float* b1     = (const float*)d_in[5];
    const float* W2     = (const float*)d_in[6];
    const float* a_src2 = (const float*)d_in[7];
    const float* a_dst2 = (const float*)d_in[8];
    const float* b2     = (const float*)d_in[9];
    float* out = (float*)d_out;

    char* w = (char*)d_ws;
    size_t off = 0;
    auto alloc = [&](size_t bytes) {
        void* p = w + off; off += (bytes + 255) & ~(size_t)255; return p;
    };
    ushort_t* h1       = (ushort_t*)alloc((size_t)N_NODES * C1 * 2);
    ushort_t* w1s      = (ushort_t*)alloc((size_t)IN_DIM * C1 * 2);
    float*    as1      = (float*)   alloc((size_t)N_NODES * 4 * 4);
    float*    ad1      = (float*)   alloc((size_t)N_NODES * 4 * 4);
    float*    pp       = (float*)   alloc((size_t)N_NODES * 2 * 4);
    int*      row_start= (int*)     alloc((size_t)(N_NODES + 1) * 4);
    int*      edge_src = (int*)     alloc((size_t)ET * 4);
    uint2*    bucketed = (uint2*)   alloc((size_t)ET * 8);
    int*      HT       = (int*)     alloc((size_t)SCAN_N * 4);
    int*      HToff    = (int*)     alloc((size_t)SCAN_N * 4);
    int*      bsum     = (int*)     alloc((size_t)NBUCKET * 4);
    int*      boff     = (int*)     alloc((size_t)NBUCKET * 4);

    k_hist<<<NBH, 256, 0, stream>>>(ei, HT, W1, w1s);
    k_blksum<<<NBUCKET, 256, 0, stream>>>(HT, bsum);
    k_bscan<<<1, 256, 0, stream>>>(bsum, boff);
    k_apply<<<NBUCKET, 256, 0, stream>>>(HT, boff, HToff);
    k_bucket_scatter<<<NBH, 256, 0, stream>>>(ei, HToff, bucketed);
    k_fine<<<NBUCKET, 256, 0, stream>>>(bucketed, HToff, row_start, edge_src);

    int nwave = (N_NODES + 15) / 16;                 // 3125 waves
    k_gemm1<<<(nwave + 3) / 4, 256, 0, stream>>>(x, w1s, a_src1, a_dst1, h1, as1, ad1);
    k_agg1<<<2 * (N_NODES / 4), 256, 0, stream>>>(h1, as1, ad1, row_start, edge_src,
                                                  b1, W2, pp);
    k_agg2<<<N_NODES / 4, 256, 0, stream>>>(pp, row_start, edge_src,
                                            a_src2, a_dst2, b2, out);
}

// Round 11
// 213.661 us; speedup vs baseline: 1.0329x; 1.0329x over previous
//
#include <hip/hip_runtime.h>
#include <hip/hip_bf16.h>

#define N_NODES 50000
#define N_EDGES 800000
#define ET      (N_EDGES + N_NODES)   // edges + self loops = 850000
#define IN_DIM  128
#define HID     64
#define HEADS   4
#define C1      (HEADS * HID)         // 256
#define NEG_SLOPE 0.2f

#define NBH     256                    // histogram/scatter blocks
#define NBUCKET 196                    // ceil(50000/256) coarse buckets (dst>>8)
#define SCAN_N  (NBUCKET * NBH)        // 50176

typedef unsigned short ushort_t;
typedef __attribute__((ext_vector_type(8))) short bf16x8;
typedef __attribute__((ext_vector_type(4))) float f32x4;

__device__ __forceinline__ float asf(unsigned int u) {
    union { unsigned int i; float f; } c; c.i = u; return c.f;
}
__device__ __forceinline__ float bf2f(ushort_t u) {
    return asf(((unsigned int)u) << 16);
}
__device__ __forceinline__ ushort_t f2bf(float f) {
    union { float f; unsigned int i; } c; c.f = f;
    unsigned int r = c.i + 0x7fffu + ((c.i >> 16) & 1u);   // RNE
    return (ushort_t)(r >> 16);
}
__device__ __forceinline__ float lrelu(float x) { return x > 0.f ? x : NEG_SLOPE * x; }

__device__ __forceinline__ float wave_sum(float v) {
    #pragma unroll
    for (int off = 32; off > 0; off >>= 1) v += __shfl_xor(v, off, 64);
    return v;
}

__device__ __forceinline__ int load_idx(const int* ei, int elem, int is64) {
    return is64 ? ei[2 * elem] : ei[elem];   // little-endian low word
}

// int64 edge_index detector (int64 data has all-zero high words).
__device__ __forceinline__ int detect64(const int* __restrict__ ei) {
    int lane = threadIdx.x & 63;
    unsigned long long nz = __ballot(lane < 32 && ei[2 * lane + 1] != 0);
    return nz == 0ull;
}

// ---------------- CSR phase 1: coarse histogram (+ W1 swizzle + bucket totals) ----------------
__global__ __launch_bounds__(256) void k_hist(const int* __restrict__ ei,
                                              int* __restrict__ HT,
                                              int* __restrict__ bucket_tot,
                                              const float* __restrict__ W1,
                                              ushort_t* __restrict__ w1s) {
    __shared__ int lcnt[NBUCKET];
    int f = detect64(ei);
    if (threadIdx.x < NBUCKET) lcnt[threadIdx.x] = 0;
    if (threadIdx.x < 128) {           // fold: W1 -> bf16 B-fragment swizzle
        int o = blockIdx.x * 128 + threadIdx.x;
        int j = o & 7, l = (o >> 3) & 63, c = (o >> 9) & 3, t = o >> 11;
        int k = c * 32 + ((l >> 4) << 3) + j;
        int n = (t << 4) + (l & 15);
        w1s[o] = f2bf(W1[k * C1 + n]);
    }
    __syncthreads();
    for (int e = blockIdx.x * 256 + threadIdx.x; e < ET; e += NBH * 256) {
        int d = (e < N_EDGES) ? load_idx(ei, N_EDGES + e, f) : e - N_EDGES;
        atomicAdd(&lcnt[d >> 8], 1);        // LDS atomic
    }
    __syncthreads();
    if (threadIdx.x < NBUCKET) {
        int c = lcnt[threadIdx.x];
        HT[threadIdx.x * NBH + blockIdx.x] = c;
        atomicAdd(&bucket_tot[threadIdx.x], c);   // replaces k_blksum
    }
}

// ---------------- CSR phase 2: scan bucket totals + apply within buckets ----------------
__global__ __launch_bounds__(256) void k_bscan(const int* __restrict__ bucket_tot,
                                               int* __restrict__ boff) {
    int tid = threadIdx.x, lane = tid & 63, wid = tid >> 6;
    int v = (tid < NBUCKET) ? bucket_tot[tid] : 0;
    int x = v;
    #pragma unroll
    for (int off = 1; off < 64; off <<= 1) {
        int t = __shfl_up(x, off, 64);
        if (lane >= off) x += t;
    }
    __shared__ int ws[4];
    if (lane == 63) ws[wid] = x;
    __syncthreads();
    int add = 0;
    for (int w = 0; w < 4; ++w) if (w < wid) add += ws[w];
    x += add;
    if (tid < NBUCKET) boff[tid] = x - v;
}

__global__ __launch_bounds__(256) void k_apply(const int* __restrict__ v,
                                               const int* __restrict__ boff,
                                               int* __restrict__ out) {
    int i = blockIdx.x * 256 + threadIdx.x;
    int lane = threadIdx.x & 63, wid = threadIdx.x >> 6;
    int val = v[i];
    int x = val;
    #pragma unroll
    for (int off = 1; off < 64; off <<= 1) {
        int t = __shfl_up(x, off, 64);
        if (lane >= off) x += t;
    }
    __shared__ int ws[4];
    if (lane == 63) ws[wid] = x;
    __syncthreads();
    int add = boff[blockIdx.x];
    for (int w = 0; w < 4; ++w) if (w < wid) add += ws[w];
    out[i] = add + x - val;
}

// ---------------- CSR phase 3: bucket scatter (LDS-atomic ranks) ----------------
__global__ __launch_bounds__(256) void k_bucket_scatter(const int* __restrict__ ei,
                                                        const int* __restrict__ HToff,
                                                        uint2* __restrict__ bucketed) {
    __shared__ int lbase[NBUCKET];
    int f = detect64(ei);
    if (threadIdx.x < NBUCKET)
        lbase[threadIdx.x] = HToff[threadIdx.x * NBH + blockIdx.x];
    __syncthreads();
    for (int e = blockIdx.x * 256 + threadIdx.x; e < ET; e += NBH * 256) {
        int s, d;
        if (e < N_EDGES) { s = load_idx(ei, e, f); d = load_idx(ei, N_EDGES + e, f); }
        else             { s = d = e - N_EDGES; }
        int pos = atomicAdd(&lbase[d >> 8], 1);
        bucketed[pos] = make_uint2((unsigned)s, (unsigned)d);
    }
}

// ---------------- CSR phase 4: per-bucket fine CSR ----------------
__global__ __launch_bounds__(256) void k_fine(const uint2* __restrict__ bucketed,
                                              const int* __restrict__ HToff,
                                              int* __restrict__ row_start,
                                              int* __restrict__ edge_src) {
    __shared__ int fcnt[256];
    __shared__ int fcur[256];
    __shared__ int ws[4];
    int b = blockIdx.x, tid = threadIdx.x;
    int lane = tid & 63, wid = tid >> 6;
    int estart = HToff[b * NBH];
    int eend   = (b + 1 < NBUCKET) ? HToff[(b + 1) * NBH] : ET;
    fcnt[tid] = 0;
    __syncthreads();
    for (int i = estart + tid; i < eend; i += 256)
        atomicAdd(&fcnt[bucketed[i].y & 255], 1);
    __syncthreads();
    int v = fcnt[tid];
    int x = v;
    #pragma unroll
    for (int off = 1; off < 64; off <<= 1) {
        int t = __shfl_up(x, off, 64);
        if (lane >= off) x += t;
    }
    if (lane == 63) ws[wid] = x;
    __syncthreads();
    int add = 0;
    for (int w = 0; w < 4; ++w) if (w < wid) add += ws[w];
    int excl = add + x - v;
    int node = b * 256 + tid;
    if (node <= N_NODES) row_start[node] = estart + excl;
    fcur[tid] = estart + excl;
    __syncthreads();
    for (int i = estart + tid; i < eend; i += 256) {
        uint2 u = bucketed[i];
        int pos = atomicAdd(&fcur[u.y & 255], 1);
        edge_src[pos] = (int)u.x;
    }
}

// ---------------- Layer 1 GEMM (MFMA) + fused attention-logit epilogue ----------------
__global__ __launch_bounds__(256) void k_gemm1(const float* __restrict__ x,
                                               const ushort_t* __restrict__ w1s,
                                               const float* __restrict__ a_src1,
                                               const float* __restrict__ a_dst1,
                                               ushort_t* __restrict__ h1,
                                               float* __restrict__ as1,
                                               float* __restrict__ ad1) {
    int lane = threadIdx.x & 63;
    int wave = (blockIdx.x * 256 + threadIdx.x) >> 6;
    int row0 = wave * 16;
    if (row0 >= N_NODES) return;
    int quad = lane >> 4, mrow = lane & 15;

    f32x4 acc[16];
    #pragma unroll
    for (int t = 0; t < 16; ++t) acc[t] = (f32x4){0.f, 0.f, 0.f, 0.f};

    const float* xrow = x + (size_t)(row0 + mrow) * IN_DIM + quad * 8;
    #pragma unroll
    for (int c = 0; c < 4; ++c) {
        float4 xa = *(const float4*)(xrow + c * 32);
        float4 xb = *(const float4*)(xrow + c * 32 + 4);
        bf16x8 a;
        a[0] = (short)f2bf(xa.x); a[1] = (short)f2bf(xa.y);
        a[2] = (short)f2bf(xa.z); a[3] = (short)f2bf(xa.w);
        a[4] = (short)f2bf(xb.x); a[5] = (short)f2bf(xb.y);
        a[6] = (short)f2bf(xb.z); a[7] = (short)f2bf(xb.w);
        #pragma unroll
        for (int t = 0; t < 16; ++t) {
            bf16x8 b = *(const bf16x8*)(w1s + (((t * 4 + c) * 64 + lane) << 3));
            acc[t] = __builtin_amdgcn_mfma_f32_16x16x32_bf16(a, b, acc[t], 0, 0, 0);
        }
    }

    #pragma unroll
    for (int t = 0; t < 16; ++t) {
        int col = t * 16 + mrow;
        #pragma unroll
        for (int r = 0; r < 4; ++r) {
            h1[(size_t)(row0 + quad * 4 + r) * C1 + col] = f2bf(acc[t][r]);
        }
    }

    float asv[16], adv[16];
    #pragma unroll
    for (int t = 0; t < 16; ++t) {
        asv[t] = a_src1[t * 16 + mrow];
        adv[t] = a_dst1[t * 16 + mrow];
    }
    #pragma unroll
    for (int r = 0; r < 4; ++r) {
        float ps[4] = {0.f, 0.f, 0.f, 0.f};
        float pd[4] = {0.f, 0.f, 0.f, 0.f};
        #pragma unroll
        for (int t = 0; t < 16; ++t) {
            ps[t >> 2] += acc[t][r] * asv[t];
            pd[t >> 2] += acc[t][r] * adv[t];
        }
        #pragma unroll
        for (int h = 0; h < 4; ++h) {
            #pragma unroll
            for (int off = 1; off < 16; off <<= 1) {
                ps[h] += __shfl_xor(ps[h], off, 64);
                pd[h] += __shfl_xor(pd[h], off, 64);
            }
        }
        if (mrow == 0) {
            int rr = row0 + quad * 4 + r;
            #pragma unroll
            for (int h = 0; h < 4; ++h) {
                as1[rr * 4 + h] = ps[h];
                ad1[rr * 4 + h] = pd[h];
            }
        }
    }
}

// ---------------- Layer 1 softmax-agg + bias/ReLU + fused layer-2 projection (r7 form) ----------------
__global__ __launch_bounds__(256) void k_agg1(const ushort_t* __restrict__ h1,
                                              const float* __restrict__ as1,
                                              const float* __restrict__ ad1,
                                              const int* __restrict__ row_start,
                                              const int* __restrict__ edge_src,
                                              const float* __restrict__ b1,
                                              const float* __restrict__ W2,
                                              const float* __restrict__ a_src2,
                                              const float* __restrict__ a_dst2,
                                              float2* __restrict__ pk,
                                              float* __restrict__ ad2) {
    __shared__ float wbuf[4][64][4];   // [wave][chunk-pos][head]
    int lane = threadIdx.x & 63;
    int wid  = threadIdx.x >> 6;
    int node = blockIdx.x * 4 + wid;
    int rs = row_start[node], re = row_start[node + 1];
    float4 ad = *(const float4*)&ad1[node * 4];
    const int head = lane >> 4;

    float4 acc = make_float4(0.f, 0.f, 0.f, 0.f);
    float4 den = make_float4(0.f, 0.f, 0.f, 0.f);

    for (int base = rs; base < re; base += 64) {
        int i = base + lane;
        int s_l = 0;
        float4 w = make_float4(0.f, 0.f, 0.f, 0.f);
        if (i < re) {
            s_l = edge_src[i];
            float4 av = *(const float4*)&as1[s_l * 4];
            w.x = __expf(lrelu(av.x + ad.x));
            w.y = __expf(lrelu(av.y + ad.y));
            w.z = __expf(lrelu(av.z + ad.z));
            w.w = __expf(lrelu(av.w + ad.w));
        }
        den.x += w.x; den.y += w.y; den.z += w.z; den.w += w.w;
        *(float4*)&wbuf[wid][lane][0] = w;
        int m = re - base; if (m > 64) m = 64;
        int j = 0;
        for (; j + 4 <= m; j += 4) {
            int s0 = __builtin_amdgcn_readlane(s_l, j + 0);
            int s1 = __builtin_amdgcn_readlane(s_l, j + 1);
            int s2 = __builtin_amdgcn_readlane(s_l, j + 2);
            int s3 = __builtin_amdgcn_readlane(s_l, j + 3);
            uint2 p0 = *(const uint2*)(h1 + (size_t)s0 * C1 + lane * 4);
            uint2 p1 = *(const uint2*)(h1 + (size_t)s1 * C1 + lane * 4);
            uint2 p2 = *(const uint2*)(h1 + (size_t)s2 * C1 + lane * 4);
            uint2 p3 = *(const uint2*)(h1 + (size_t)s3 * C1 + lane * 4);
            float g0 = wbuf[wid][j + 0][head];
            float g1 = wbuf[wid][j + 1][head];
            float g2 = wbuf[wid][j + 2][head];
            float g3 = wbuf[wid][j + 3][head];
            acc.x += g0 * asf(p0.x << 16);
            acc.y += g0 * asf(p0.x & 0xffff0000u);
            acc.z += g0 * asf(p0.y << 16);
            acc.w += g0 * asf(p0.y & 0xffff0000u);
            acc.x += g1 * asf(p1.x << 16);
            acc.y += g1 * asf(p1.x & 0xffff0000u);
            acc.z += g1 * asf(p1.y << 16);
            acc.w += g1 * asf(p1.y & 0xffff0000u);
            acc.x += g2 * asf(p2.x << 16);
            acc.y += g2 * asf(p2.x & 0xffff0000u);
            acc.z += g2 * asf(p2.y << 16);
            acc.w += g2 * asf(p2.y & 0xffff0000u);
            acc.x += g3 * asf(p3.x << 16);
            acc.y += g3 * asf(p3.x & 0xffff0000u);
            acc.z += g3 * asf(p3.y << 16);
            acc.w += g3 * asf(p3.y & 0xffff0000u);
        }
        for (; j < m; ++j) {
            int s0 = __builtin_amdgcn_readlane(s_l, j);
            uint2 p0 = *(const uint2*)(h1 + (size_t)s0 * C1 + lane * 4);
            float g0 = wbuf[wid][j][head];
            acc.x += g0 * asf(p0.x << 16);
            acc.y += g0 * asf(p0.x & 0xffff0000u);
            acc.z += g0 * asf(p0.y << 16);
            acc.w += g0 * asf(p0.y & 0xffff0000u);
        }
    }

    float d0 = wave_sum(den.x), d1 = wave_sum(den.y);
    float d2 = wave_sum(den.z), d3 = wave_sum(den.w);
    float dh = head == 0 ? d0 : head == 1 ? d1 : head == 2 ? d2 : d3;
    float inv = 1.f / (dh + 1e-16f);
    float4 bv = *(const float4*)&b1[lane * 4];
    float o0 = fmaxf(acc.x * inv + bv.x, 0.f);
    float o1 = fmaxf(acc.y * inv + bv.y, 0.f);
    float o2 = fmaxf(acc.z * inv + bv.z, 0.f);
    float o3 = fmaxf(acc.w * inv + bv.w, 0.f);
    float4 wv = *(const float4*)&W2[lane * 4];
    float sum = o0 * wv.x + o1 * wv.y + o2 * wv.z + o3 * wv.w;
    sum = wave_sum(sum);
    if (lane == 0) {
        float2 p; p.x = sum * a_src2[0]; p.y = sum;
        pk[node]  = p;
        ad2[node] = sum * a_dst2[0];
    }
}

// ---------------- Layer 2 softmax-agg + sigmoid ----------------
__global__ __launch_bounds__(256) void k_agg2(const float2* __restrict__ pk,
                                              const float* __restrict__ ad2,
                                              const int* __restrict__ row_start,
                                              const int* __restrict__ edge_src,
                                              const float* __restrict__ b2,
                                              float* __restrict__ outp) {
    int lane = threadIdx.x & 63;
    int node = blockIdx.x * 4 + (threadIdx.x >> 6);
    int rs = row_start[node], re = row_start[node + 1];
    float adv = ad2[node];
    float se = 0.f, wsm = 0.f;
    for (int i = rs + lane; i < re; i += 64) {
        int s = edge_src[i];
        float2 p = pk[s];
        float w = __expf(lrelu(p.x + adv));
        se += w; wsm += w * p.y;
    }
    se = wave_sum(se); wsm = wave_sum(wsm);
    if (lane == 0) {
        float v = wsm / (se + 1e-16f) + b2[0];
        outp[node] = 1.f / (1.f + __expf(-v));
    }
}

extern "C" void kernel_launch(void* const* d_in, const int* in_sizes, int n_in,
                              void* d_out, int out_size, void* d_ws, size_t ws_size,
                              hipStream_t stream) {
    (void)in_sizes; (void)n_in; (void)out_size; (void)ws_size;
    const float* x      = (const float*)d_in[0];
    const int*   ei     = (const int*)  d_in[1];
    const float* W1     = (const float*)d_in[2];
    const float* a_src1 = (const float*)d_in[3];
    const float* a_dst1 = (const float*)d_in[4];
    const float* b1     = (const float*)d_in[5];
    const float* W2     = (const float*)d_in[6];
    const float* a_src2 = (const float*)d_in[7];
    const float* a_dst2 = (const float*)d_in[8];
    const float* b2     = (const float*)d_in[9];
    float* out = (float*)d_out;

    char* w = (char*)d_ws;
    size_t off = 0;
    auto alloc = [&](size_t bytes) {
        void* p = w + off; off += (bytes + 255) & ~(size_t)255; return p;
    };
    ushort_t* h1        = (ushort_t*)alloc((size_t)N_NODES * C1 * 2);
    ushort_t* w1s       = (ushort_t*)alloc((size_t)IN_DIM * C1 * 2);
    float*    as1       = (float*)   alloc((size_t)N_NODES * 4 * 4);
    float*    ad1       = (float*)   alloc((size_t)N_NODES * 4 * 4);
    float2*   pk        = (float2*)  alloc((size_t)N_NODES * 8);
    float*    ad2       = (float*)   alloc((size_t)N_NODES * 4);
    int*      row_start = (int*)     alloc((size_t)(N_NODES + 1) * 4);
    int*      edge_src  = (int*)     alloc((size_t)ET * 4);
    uint2*    bucketed  = (uint2*)   alloc((size_t)ET * 8);
    int*      HT        = (int*)     alloc((size_t)SCAN_N * 4);
    int*      HToff     = (int*)     alloc((size_t)SCAN_N * 4);
    int*      bucket_tot= (int*)     alloc((size_t)NBUCKET * 4);
    int*      boff      = (int*)     alloc((size_t)NBUCKET * 4);

    hipMemsetAsync(bucket_tot, 0, NBUCKET * sizeof(int), stream);
    k_hist<<<NBH, 256, 0, stream>>>(ei, HT, bucket_tot, W1, w1s);
    k_bscan<<<1, 256, 0, stream>>>(bucket_tot, boff);
    k_apply<<<NBUCKET, 256, 0, stream>>>(HT, boff, HToff);
    k_bucket_scatter<<<NBH, 256, 0, stream>>>(ei, HToff, bucketed);
    k_fine<<<NBUCKET, 256, 0, stream>>>(bucketed, HToff, row_start, edge_src);

    int nwave = (N_NODES + 15) / 16;                 // 3125 waves
    k_gemm1<<<(nwave + 3) / 4, 256, 0, stream>>>(x, w1s, a_src1, a_dst1, h1, as1, ad1);
    k_agg1<<<N_NODES / 4, 256, 0, stream>>>(h1, as1, ad1, row_start, edge_src,
                                            b1, W2, a_src2, a_dst2, pk, ad2);
    k_agg2<<<N_NODES / 4, 256, 0, stream>>>(pk, ad2, row_start, edge_src, b2, out);
}

// Round 12
// 188.676 us; speedup vs baseline: 1.1697x; 1.1324x over previous
//
#include <hip/hip_runtime.h>
#include <hip/hip_bf16.h>

#define N_NODES 50000
#define N_EDGES 800000
#define ET      (N_EDGES + N_NODES)   // edges + self loops = 850000
#define IN_DIM  128
#define HID     64
#define HEADS   4
#define C1      (HEADS * HID)         // 256
#define NEG_SLOPE 0.2f

#define NBH     256                    // histogram/scatter blocks
#define NBUCKET 196                    // ceil(50000/256) coarse buckets (dst>>8)
#define SCAN_N  (NBUCKET * NBH)        // 50176

typedef unsigned short ushort_t;
typedef unsigned char  u8;
typedef __attribute__((ext_vector_type(8))) short bf16x8;
typedef __attribute__((ext_vector_type(4))) float f32x4;

#ifndef __has_builtin
#define __has_builtin(x) 0
#endif

__device__ __forceinline__ float asf(unsigned int u) {
    union { unsigned int i; float f; } c; c.i = u; return c.f;
}
__device__ __forceinline__ ushort_t f2bf(float f) {
    union { float f; unsigned int i; } c; c.f = f;
    unsigned int r = c.i + 0x7fffu + ((c.i >> 16) & 1u);   // RNE
    return (ushort_t)(r >> 16);
}
__device__ __forceinline__ float lrelu(float x) { return x > 0.f ? x : NEG_SLOPE * x; }

// ---- fp8 e4m3fn encode/decode (HW cvt when available) ----
__device__ __forceinline__ u8 f2fp8(float f) {
#if __has_builtin(__builtin_amdgcn_cvt_pk_fp8_f32)
    int r = __builtin_amdgcn_cvt_pk_fp8_f32(f, f, 0, false);
    return (u8)(r & 0xff);
#else
    union { float f; unsigned u; } c; c.f = f;
    unsigned s = (c.u >> 24) & 0x80;
    unsigned a = c.u & 0x7fffffffu;
    if (a >= 0x43E00000u) return (u8)(s | 0x7E);      // clamp to 448
    int e = (int)(a >> 23) - 127;
    if (e >= -6) {
        unsigned m = a & 0x7fffffu;
        unsigned mant = m >> 20;
        unsigned rem  = m & 0xfffffu;
        mant += (rem > 0x80000u) || (rem == 0x80000u && (mant & 1));
        unsigned ee = (unsigned)(e + 7);
        if (mant == 8) { mant = 0; ee += 1; }
        if (ee > 15) return (u8)(s | 0x7E);
        return (u8)(s | (ee << 3) | mant);
    } else {
        float av = asf(a);
        int n = (int)(av * 512.0f + 0.5f);
        if (n >= 8) return (u8)(s | 0x08);
        return (u8)(s | n);
    }
#endif
}

__device__ __forceinline__ void fp8x4_to_f32(unsigned p, float* o) {
#if __has_builtin(__builtin_amdgcn_cvt_pk_f32_fp8)
    auto lo = __builtin_amdgcn_cvt_pk_f32_fp8((int)p, false);
    auto hi = __builtin_amdgcn_cvt_pk_f32_fp8((int)p, true);
    o[0] = lo[0]; o[1] = lo[1]; o[2] = hi[0]; o[3] = hi[1];
#else
    #pragma unroll
    for (int k = 0; k < 4; ++k) {
        unsigned u = (p >> (8 * k)) & 0xff;
        unsigned s = (u & 0x80) << 24;
        unsigned e = (u >> 3) & 15;
        unsigned m = u & 7;
        float v;
        if (e) v = asf(s | ((e + 120) << 23) | (m << 20));
        else { v = (float)m * 0.001953125f; v = (u & 0x80) ? -v : v; }
        o[k] = v;
    }
#endif
}

__device__ __forceinline__ float wave_sum(float v) {
    #pragma unroll
    for (int off = 32; off > 0; off >>= 1) v += __shfl_xor(v, off, 64);
    return v;
}

__device__ __forceinline__ int load_idx(const int* ei, int elem, int is64) {
    return is64 ? ei[2 * elem] : ei[elem];   // little-endian low word
}

// int64 edge_index detector (int64 data has all-zero high words).
__device__ __forceinline__ int detect64(const int* __restrict__ ei) {
    int lane = threadIdx.x & 63;
    unsigned long long nz = __ballot(lane < 32 && ei[2 * lane + 1] != 0);
    return nz == 0ull;
}

// ---------------- CSR phase 1: coarse histogram (+ W1 swizzle + bucket totals) ----------------
__global__ __launch_bounds__(256) void k_hist(const int* __restrict__ ei,
                                              int* __restrict__ HT,
                                              int* __restrict__ bucket_tot,
                                              const float* __restrict__ W1,
                                              ushort_t* __restrict__ w1s) {
    __shared__ int lcnt[NBUCKET];
    int f = detect64(ei);
    if (threadIdx.x < NBUCKET) lcnt[threadIdx.x] = 0;
    if (threadIdx.x < 128) {           // fold: W1 -> bf16 B-fragment swizzle
        int o = blockIdx.x * 128 + threadIdx.x;
        int j = o & 7, l = (o >> 3) & 63, c = (o >> 9) & 3, t = o >> 11;
        int k = c * 32 + ((l >> 4) << 3) + j;
        int n = (t << 4) + (l & 15);
        w1s[o] = f2bf(W1[k * C1 + n]);
    }
    __syncthreads();
    for (int e = blockIdx.x * 256 + threadIdx.x; e < ET; e += NBH * 256) {
        int d = (e < N_EDGES) ? load_idx(ei, N_EDGES + e, f) : e - N_EDGES;
        atomicAdd(&lcnt[d >> 8], 1);        // LDS atomic
    }
    __syncthreads();
    if (threadIdx.x < NBUCKET) {
        int c = lcnt[threadIdx.x];
        HT[threadIdx.x * NBH + blockIdx.x] = c;
        atomicAdd(&bucket_tot[threadIdx.x], c);
    }
}

// ---------------- CSR phase 2: per-bucket offsets (self-scans bucket totals) ----------------
__global__ __launch_bounds__(256) void k_apply(const int* __restrict__ v,
                                               const int* __restrict__ bucket_tot,
                                               int* __restrict__ out) {
    __shared__ int sbo[NBUCKET];
    __shared__ int ws[4];
    int tid = threadIdx.x, lane = tid & 63, wid = tid >> 6;
    // exclusive scan of bucket_tot (196) into sbo
    int bv = (tid < NBUCKET) ? bucket_tot[tid] : 0;
    int bx = bv;
    #pragma unroll
    for (int off = 1; off < 64; off <<= 1) {
        int t = __shfl_up(bx, off, 64);
        if (lane >= off) bx += t;
    }
    if (lane == 63) ws[wid] = bx;
    __syncthreads();
    int badd = 0;
    for (int w = 0; w < 4; ++w) if (w < wid) badd += ws[w];
    if (tid < NBUCKET) sbo[tid] = badd + bx - bv;
    __syncthreads();
    // scan this bucket's per-block counts
    int i = blockIdx.x * 256 + tid;
    int val = v[i];
    int x = val;
    #pragma unroll
    for (int off = 1; off < 64; off <<= 1) {
        int t = __shfl_up(x, off, 64);
        if (lane >= off) x += t;
    }
    __shared__ int ws2[4];
    if (lane == 63) ws2[wid] = x;
    __syncthreads();
    int add = sbo[blockIdx.x];
    for (int w = 0; w < 4; ++w) if (w < wid) add += ws2[w];
    out[i] = add + x - val;
}

// ---------------- CSR phase 3: bucket scatter (LDS-atomic ranks) ----------------
__global__ __launch_bounds__(256) void k_bucket_scatter(const int* __restrict__ ei,
                                                        const int* __restrict__ HToff,
                                                        uint2* __restrict__ bucketed) {
    __shared__ int lbase[NBUCKET];
    int f = detect64(ei);
    if (threadIdx.x < NBUCKET)
        lbase[threadIdx.x] = HToff[threadIdx.x * NBH + blockIdx.x];
    __syncthreads();
    for (int e = blockIdx.x * 256 + threadIdx.x; e < ET; e += NBH * 256) {
        int s, d;
        if (e < N_EDGES) { s = load_idx(ei, e, f); d = load_idx(ei, N_EDGES + e, f); }
        else             { s = d = e - N_EDGES; }
        int pos = atomicAdd(&lbase[d >> 8], 1);
        bucketed[pos] = make_uint2((unsigned)s, (unsigned)d);
    }
}

// ---------------- CSR phase 4: per-bucket fine CSR ----------------
__global__ __launch_bounds__(256) void k_fine(const uint2* __restrict__ bucketed,
                                              const int* __restrict__ HToff,
                                              int* __restrict__ row_start,
                                              int* __restrict__ edge_src) {
    __shared__ int fcnt[256];
    __shared__ int fcur[256];
    __shared__ int ws[4];
    int b = blockIdx.x, tid = threadIdx.x;
    int lane = tid & 63, wid = tid >> 6;
    int estart = HToff[b * NBH];
    int eend   = (b + 1 < NBUCKET) ? HToff[(b + 1) * NBH] : ET;
    fcnt[tid] = 0;
    __syncthreads();
    for (int i = estart + tid; i < eend; i += 256)
        atomicAdd(&fcnt[bucketed[i].y & 255], 1);
    __syncthreads();
    int v = fcnt[tid];
    int x = v;
    #pragma unroll
    for (int off = 1; off < 64; off <<= 1) {
        int t = __shfl_up(x, off, 64);
        if (lane >= off) x += t;
    }
    if (lane == 63) ws[wid] = x;
    __syncthreads();
    int add = 0;
    for (int w = 0; w < 4; ++w) if (w < wid) add += ws[w];
    int excl = add + x - v;
    int node = b * 256 + tid;
    if (node <= N_NODES) row_start[node] = estart + excl;
    fcur[tid] = estart + excl;
    __syncthreads();
    for (int i = estart + tid; i < eend; i += 256) {
        uint2 u = bucketed[i];
        int pos = atomicAdd(&fcur[u.y & 255], 1);
        edge_src[pos] = (int)u.x;
    }
}

// ---------------- Layer 1 GEMM (MFMA) + fused attention-logit epilogue, fp8 h1 ----------------
__global__ __launch_bounds__(256) void k_gemm1(const float* __restrict__ x,
                                               const ushort_t* __restrict__ w1s,
                                               const float* __restrict__ a_src1,
                                               const float* __restrict__ a_dst1,
                                               u8* __restrict__ h1,
                                               float* __restrict__ as1,
                                               float* __restrict__ ad1) {
    int lane = threadIdx.x & 63;
    int wave = (blockIdx.x * 256 + threadIdx.x) >> 6;
    int row0 = wave * 16;
    if (row0 >= N_NODES) return;
    int quad = lane >> 4, mrow = lane & 15;

    f32x4 acc[16];
    #pragma unroll
    for (int t = 0; t < 16; ++t) acc[t] = (f32x4){0.f, 0.f, 0.f, 0.f};

    const float* xrow = x + (size_t)(row0 + mrow) * IN_DIM + quad * 8;
    #pragma unroll
    for (int c = 0; c < 4; ++c) {
        float4 xa = *(const float4*)(xrow + c * 32);
        float4 xb = *(const float4*)(xrow + c * 32 + 4);
        bf16x8 a;
        a[0] = (short)f2bf(xa.x); a[1] = (short)f2bf(xa.y);
        a[2] = (short)f2bf(xa.z); a[3] = (short)f2bf(xa.w);
        a[4] = (short)f2bf(xb.x); a[5] = (short)f2bf(xb.y);
        a[6] = (short)f2bf(xb.z); a[7] = (short)f2bf(xb.w);
        #pragma unroll
        for (int t = 0; t < 16; ++t) {
            bf16x8 b = *(const bf16x8*)(w1s + (((t * 4 + c) * 64 + lane) << 3));
            acc[t] = __builtin_amdgcn_mfma_f32_16x16x32_bf16(a, b, acc[t], 0, 0, 0);
        }
    }

    // h1 store (fp8): acc[t][r] -> h1[row0 + quad*4 + r][t*16 + mrow]
    #pragma unroll
    for (int t = 0; t < 16; ++t) {
        int col = t * 16 + mrow;
        #pragma unroll
        for (int r = 0; r < 4; ++r) {
            h1[(size_t)(row0 + quad * 4 + r) * C1 + col] = f2fp8(acc[t][r]);
        }
    }

    float asv[16], adv[16];
    #pragma unroll
    for (int t = 0; t < 16; ++t) {
        asv[t] = a_src1[t * 16 + mrow];
        adv[t] = a_dst1[t * 16 + mrow];
    }
    #pragma unroll
    for (int r = 0; r < 4; ++r) {
        float ps[4] = {0.f, 0.f, 0.f, 0.f};
        float pd[4] = {0.f, 0.f, 0.f, 0.f};
        #pragma unroll
        for (int t = 0; t < 16; ++t) {
            ps[t >> 2] += acc[t][r] * asv[t];
            pd[t >> 2] += acc[t][r] * adv[t];
        }
        #pragma unroll
        for (int h = 0; h < 4; ++h) {
            #pragma unroll
            for (int off = 1; off < 16; off <<= 1) {
                ps[h] += __shfl_xor(ps[h], off, 64);
                pd[h] += __shfl_xor(pd[h], off, 64);
            }
        }
        if (mrow == 0) {
            int rr = row0 + quad * 4 + r;
            #pragma unroll
            for (int h = 0; h < 4; ++h) {
                as1[rr * 4 + h] = ps[h];
                ad1[rr * 4 + h] = pd[h];
            }
        }
    }
}

// ---------------- Layer 1 softmax-agg + bias/ReLU + fused layer-2 projection (fp8 gather) ----------------
__global__ __launch_bounds__(256) void k_agg1(const u8* __restrict__ h1,
                                              const float* __restrict__ as1,
                                              const float* __restrict__ ad1,
                                              const int* __restrict__ row_start,
                                              const int* __restrict__ edge_src,
                                              const float* __restrict__ b1,
                                              const float* __restrict__ W2,
                                              const float* __restrict__ a_src2,
                                              const float* __restrict__ a_dst2,
                                              float2* __restrict__ pk,
                                              float* __restrict__ ad2) {
    __shared__ float wbuf[4][64][4];   // [wave][chunk-pos][head]
    int lane = threadIdx.x & 63;
    int wid  = threadIdx.x >> 6;
    int node = blockIdx.x * 4 + wid;
    int rs = row_start[node], re = row_start[node + 1];
    float4 ad = *(const float4*)&ad1[node * 4];
    const int head = lane >> 4;

    float4 acc = make_float4(0.f, 0.f, 0.f, 0.f);
    float4 den = make_float4(0.f, 0.f, 0.f, 0.f);

    for (int base = rs; base < re; base += 64) {
        int i = base + lane;
        int s_l = 0;
        float4 w = make_float4(0.f, 0.f, 0.f, 0.f);
        if (i < re) {
            s_l = edge_src[i];
            float4 av = *(const float4*)&as1[s_l * 4];
            w.x = __expf(lrelu(av.x + ad.x));
            w.y = __expf(lrelu(av.y + ad.y));
            w.z = __expf(lrelu(av.z + ad.z));
            w.w = __expf(lrelu(av.w + ad.w));
        }
        den.x += w.x; den.y += w.y; den.z += w.z; den.w += w.w;
        *(float4*)&wbuf[wid][lane][0] = w;
        int m = re - base; if (m > 64) m = 64;
        int j = 0;
        for (; j + 4 <= m; j += 4) {
            int s0 = __builtin_amdgcn_readlane(s_l, j + 0);
            int s1 = __builtin_amdgcn_readlane(s_l, j + 1);
            int s2 = __builtin_amdgcn_readlane(s_l, j + 2);
            int s3 = __builtin_amdgcn_readlane(s_l, j + 3);
            unsigned p0 = *(const unsigned*)(h1 + (size_t)s0 * C1 + lane * 4);
            unsigned p1 = *(const unsigned*)(h1 + (size_t)s1 * C1 + lane * 4);
            unsigned p2 = *(const unsigned*)(h1 + (size_t)s2 * C1 + lane * 4);
            unsigned p3 = *(const unsigned*)(h1 + (size_t)s3 * C1 + lane * 4);
            float g0 = wbuf[wid][j + 0][head];
            float g1 = wbuf[wid][j + 1][head];
            float g2 = wbuf[wid][j + 2][head];
            float g3 = wbuf[wid][j + 3][head];
            float v0[4], v1[4], v2[4], v3[4];
            fp8x4_to_f32(p0, v0);
            fp8x4_to_f32(p1, v1);
            fp8x4_to_f32(p2, v2);
            fp8x4_to_f32(p3, v3);
            acc.x += g0 * v0[0]; acc.y += g0 * v0[1]; acc.z += g0 * v0[2]; acc.w += g0 * v0[3];
            acc.x += g1 * v1[0]; acc.y += g1 * v1[1]; acc.z += g1 * v1[2]; acc.w += g1 * v1[3];
            acc.x += g2 * v2[0]; acc.y += g2 * v2[1]; acc.z += g2 * v2[2]; acc.w += g2 * v2[3];
            acc.x += g3 * v3[0]; acc.y += g3 * v3[1]; acc.z += g3 * v3[2]; acc.w += g3 * v3[3];
        }
        for (; j < m; ++j) {
            int s0 = __builtin_amdgcn_readlane(s_l, j);
            unsigned p0 = *(const unsigned*)(h1 + (size_t)s0 * C1 + lane * 4);
            float g0 = wbuf[wid][j][head];
            float v0[4];
            fp8x4_to_f32(p0, v0);
            acc.x += g0 * v0[0]; acc.y += g0 * v0[1]; acc.z += g0 * v0[2]; acc.w += g0 * v0[3];
        }
    }

    float d0 = wave_sum(den.x), d1 = wave_sum(den.y);
    float d2 = wave_sum(den.z), d3 = wave_sum(den.w);
    float dh = head == 0 ? d0 : head == 1 ? d1 : head == 2 ? d2 : d3;
    float inv = 1.f / (dh + 1e-16f);
    float4 bv = *(const float4*)&b1[lane * 4];
    float o0 = fmaxf(acc.x * inv + bv.x, 0.f);
    float o1 = fmaxf(acc.y * inv + bv.y, 0.f);
    float o2 = fmaxf(acc.z * inv + bv.z, 0.f);
    float o3 = fmaxf(acc.w * inv + bv.w, 0.f);
    float4 wv = *(const float4*)&W2[lane * 4];
    float sum = o0 * wv.x + o1 * wv.y + o2 * wv.z + o3 * wv.w;
    sum = wave_sum(sum);
    if (lane == 0) {
        float2 p; p.x = sum * a_src2[0]; p.y = sum;
        pk[node]  = p;
        ad2[node] = sum * a_dst2[0];
    }
}

// ---------------- Layer 2 softmax-agg + sigmoid ----------------
__global__ __launch_bounds__(256) void k_agg2(const float2* __restrict__ pk,
                                              const float* __restrict__ ad2,
                                              const int* __restrict__ row_start,
                                              const int* __restrict__ edge_src,
                                              const float* __restrict__ b2,
                                              float* __restrict__ outp) {
    int lane = threadIdx.x & 63;
    int node = blockIdx.x * 4 + (threadIdx.x >> 6);
    int rs = row_start[node], re = row_start[node + 1];
    float adv = ad2[node];
    float se = 0.f, wsm = 0.f;
    for (int i = rs + lane; i < re; i += 64) {
        int s = edge_src[i];
        float2 p = pk[s];
        float w = __expf(lrelu(p.x + adv));
        se += w; wsm += w * p.y;
    }
    se = wave_sum(se); wsm = wave_sum(wsm);
    if (lane == 0) {
        float v = wsm / (se + 1e-16f) + b2[0];
        outp[node] = 1.f / (1.f + __expf(-v));
    }
}

extern "C" void kernel_launch(void* const* d_in, const int* in_sizes, int n_in,
                              void* d_out, int out_size, void* d_ws, size_t ws_size,
                              hipStream_t stream) {
    (void)in_sizes; (void)n_in; (void)out_size; (void)ws_size;
    const float* x      = (const float*)d_in[0];
    const int*   ei     = (const int*)  d_in[1];
    const float* W1     = (const float*)d_in[2];
    const float* a_src1 = (const float*)d_in[3];
    const float* a_dst1 = (const float*)d_in[4];
    const float* b1     = (const float*)d_in[5];
    const float* W2     = (const float*)d_in[6];
    const float* a_src2 = (const float*)d_in[7];
    const float* a_dst2 = (const float*)d_in[8];
    const float* b2     = (const float*)d_in[9];
    float* out = (float*)d_out;

    char* w = (char*)d_ws;
    size_t off = 0;
    auto alloc = [&](size_t bytes) {
        void* p = w + off; off += (bytes + 255) & ~(size_t)255; return p;
    };
    u8*       h1        = (u8*)      alloc((size_t)N_NODES * C1);
    ushort_t* w1s       = (ushort_t*)alloc((size_t)IN_DIM * C1 * 2);
    float*    as1       = (float*)   alloc((size_t)N_NODES * 4 * 4);
    float*    ad1       = (float*)   alloc((size_t)N_NODES * 4 * 4);
    float2*   pk        = (float2*)  alloc((size_t)N_NODES * 8);
    float*    ad2       = (float*)   alloc((size_t)N_NODES * 4);
    int*      row_start = (int*)     alloc((size_t)(N_NODES + 1) * 4);
    int*      edge_src  = (int*)     alloc((size_t)ET * 4);
    uint2*    bucketed  = (uint2*)   alloc((size_t)ET * 8);
    int*      HT        = (int*)     alloc((size_t)SCAN_N * 4);
    int*      HToff     = (int*)     alloc((size_t)SCAN_N * 4);
    int*      bucket_tot= (int*)     alloc((size_t)NBUCKET * 4);

    hipMemsetAsync(bucket_tot, 0, NBUCKET * sizeof(int), stream);
    k_hist<<<NBH, 256, 0, stream>>>(ei, HT, bucket_tot, W1, w1s);
    k_apply<<<NBUCKET, 256, 0, stream>>>(HT, bucket_tot, HToff);
    k_bucket_scatter<<<NBH, 256, 0, stream>>>(ei, HToff, bucketed);
    k_fine<<<NBUCKET, 256, 0, stream>>>(bucketed, HToff, row_start, edge_src);

    int nwave = (N_NODES + 15) / 16;                 // 3125 waves
    k_gemm1<<<(nwave + 3) / 4, 256, 0, stream>>>(x, w1s, a_src1, a_dst1, h1, as1, ad1);
    k_agg1<<<N_NODES / 4, 256, 0, stream>>>(h1, as1, ad1, row_start, edge_src,
                                            b1, W2, a_src2, a_dst2, pk, ad2);
    k_agg2<<<N_NODES / 4, 256, 0, stream>>>(pk, ad2, row_start, edge_src, b2, out);
}